// Round 21
// baseline (120.449 us; speedup 1.0000x reference)
//
#include <hip/hip_runtime.h>

// ---------------------------------------------------------------------------
// BasicAttention: dwconv3x3 -> pointwise 1x1 (C->3C) -> 4-head attention S=4096
// B=4, C=256, H=W=64, heads=4, d=64. Output f32 [B,C,H,W].
//
//  k_dw   : depthwise conv -> DWt bf16 (coalesced lane=w) + folded w_pw cvt
//  k_pw   : 256 thr / 4 waves, 32-s tiles, 2 blocks/CU (r20)
//  k_attn : flash attention, swapped QK^T, no-max softmax (r10), permuted-K
//           (r11), l via ones-MFMA, 2-tile pipelined pair body (r17).
//           NEW (r21): 8-slot KV ring (128KB), Q staged through slots 6,7
//           then released (r15 pattern); ONE vmcnt(0)+s_barrier per QUAD
//           (4 tiles) -> 16 barriers total (r12: 64->32 barriers = -4.3us).
//  Pinned-by: per-CU LDS read volume (8 waves x full K/V tile; m134 12cyc
//  b128 floor) + QK->SM->PV chain; restructures that cut LDS volume failed
//  twice (r9 spill, r18 numeric) - shelved.
// ---------------------------------------------------------------------------

typedef __attribute__((ext_vector_type(8))) __bf16 bf16x8;
typedef __attribute__((ext_vector_type(4))) float f32x4;
typedef __attribute__((ext_vector_type(16))) float f32x16;
typedef __attribute__((ext_vector_type(8))) unsigned short ushort8;
typedef __attribute__((ext_vector_type(4))) unsigned int uint4v;

#define OFF_DW 0ull
#define OFF_WB 8388608ull
#define OFF_Q  8781824ull
#define OFF_K  17170432ull
#define OFF_V  25559040ull

__device__ __forceinline__ unsigned short f2bf(float x) {
  unsigned u = __builtin_bit_cast(unsigned, x);
  u += 0x7fffu + ((u >> 16) & 1u);           // RNE
  return (unsigned short)(u >> 16);
}

__device__ __forceinline__ void gld16(const void* g, void* l) {
  __builtin_amdgcn_global_load_lds((const __attribute__((address_space(1))) void*)g,
                                   (__attribute__((address_space(3))) void*)l, 16, 0, 0);
}

__device__ __forceinline__ unsigned cvtpk(float lo, float hi) {
  unsigned r;
  asm("v_cvt_pk_bf16_f32 %0, %1, %2" : "=v"(r) : "v"(lo), "v"(hi));
  return r;
}

// ---------------- kernel 1: depthwise conv + w_pw conversion ----------------
__global__ __launch_bounds__(512) void k_dw(const float* __restrict__ x,
                                            const float* __restrict__ wdw,
                                            const float* __restrict__ wpw,
                                            unsigned short* __restrict__ dwt,
                                            unsigned short* __restrict__ wbf) {
  __shared__ float tile[64 * 65];
  const int t = threadIdx.x;
  const int h = blockIdx.x;
  const int c0 = blockIdx.y * 64;
  const int b = blockIdx.z;

  {
    int bid = blockIdx.x + 64 * blockIdx.y + 256 * blockIdx.z;   // 0..1023
    if (t < 192) {
      int idx = bid * 192 + t;
      int o = idx >> 8;
      float v = wpw[idx];
      if (o < 256) v *= 0.18033688011112042f;     // 0.125 * log2(e)
      wbf[idx] = f2bf(v);
    }
  }

  const int w = t & 63;
  const int wq = t >> 6;                          // 0..7
#pragma unroll
  for (int i = 0; i < 8; ++i) {
    int cl = wq * 8 + i;
    int c = c0 + cl;
    const float* wd = wdw + c * 9;
    const float* xb = x + ((size_t)(b * 256 + c) << 12);
    float acc = 0.f;
#pragma unroll
    for (int ky = 0; ky < 3; ++ky) {
      int hh = h + ky - 1;
      if ((unsigned)hh < 64u) {
        const float* row = xb + hh * 64;
#pragma unroll
        for (int kx = 0; kx < 3; ++kx) {
          int ww = w + kx - 1;
          if ((unsigned)ww < 64u) acc += row[ww] * wd[ky * 3 + kx];
        }
      }
    }
    tile[w * 65 + cl] = acc;
  }
  __syncthreads();
  int sl = t >> 3, cch = (t & 7) * 8;             // 64 rows x 8 chunks
  ushort8 p0;
#pragma unroll
  for (int j = 0; j < 8; ++j) p0[j] = f2bf(tile[sl * 65 + cch + j]);
  unsigned short* dst = dwt + ((size_t)(b * 4096 + h * 64 + sl)) * 256 + c0 + cch;
  *(ushort8*)dst = p0;
}

// ---------------- kernel 2: pointwise GEMM -> Q,K,Vt (2 blocks/CU) ----------
__global__ __launch_bounds__(256) void k_pw(const unsigned short* __restrict__ dwt,
                                            const unsigned short* __restrict__ wbf,
                                            unsigned short* __restrict__ q,
                                            unsigned short* __restrict__ k,
                                            unsigned short* __restrict__ v) {
  __shared__ __align__(16) unsigned char smem[57472];
  const int t = threadIdx.x;
  const int lane = t & 63, wv = t >> 6;            // wv 0..3
  const int s0 = blockIdx.x * 32;
  const int b = blockIdx.y;
  const int vb = ((lane >> 5) << 9) + (((lane & 31) ^ (lane >> 5)) << 4);
  const char* dsrc = (const char*)dwt + ((size_t)(b * 4096 + s0)) * 512;

#pragma unroll
  for (int i = 0; i < 4; ++i) {
    int I = wv * 4 + i;
    int u = ((2 * i) & 7) << 4;                    // (2I)&7 == (2i)&7
    gld16(dsrc + (size_t)I * 1024 + (vb ^ u), smem + 32768 + I * 1024);
  }
#pragma unroll
  for (int i = 0; i < 8; ++i) {
    int I = wv * 8 + i;
    int u = ((2 * i) & 7) << 4;
    gld16((const char*)wbf + (size_t)I * 1024 + (vb ^ u), smem + I * 1024);
  }
  asm volatile("s_waitcnt vmcnt(0)" ::: "memory");
  __syncthreads();

  const int c15 = lane & 15, g = lane >> 4;
  const int orow = wv * 16 + c15;                  // wave owns 16 o-rows

#pragma unroll 1
  for (int yy = 0; yy < 12; ++yy) {
    f32x4 acc[2] = {{0,0,0,0},{0,0,0,0}};
#pragma unroll
    for (int kc = 0; kc < 8; ++kc) {
      bf16x8 a = *(const bf16x8*)(smem + orow * 512 + (((kc * 4 + g) ^ (orow & 7)) << 4));
#pragma unroll
      for (int nt = 0; nt < 2; ++nt) {
        int srow = nt * 16 + c15;
        bf16x8 bb = *(const bf16x8*)(smem + 32768 + srow * 512 + (((kc * 4 + g) ^ (srow & 7)) << 4));
        acc[nt] = __builtin_amdgcn_mfma_f32_16x16x32_bf16(a, bb, acc[nt], 0, 0, 0);
      }
    }

    const int type = yy >> 2, head = yy & 3;
    const size_t bh = (size_t)(b * 4 + head);
    if (type == 2) {
#pragma unroll
      for (int nt = 0; nt < 2; ++nt)
#pragma unroll
        for (int r = 0; r < 4; ++r) {
          int d = wv * 16 + g * 4 + r;
          int sg = s0 + nt * 16 + c15;
          v[(bh * 64 + d) * 4096 + sg] = f2bf(acc[nt][r]);
        }
      __syncthreads();                             // all W(yy) reads done
    } else {
      float* ol = (float*)(smem + 49152);          // [32 s][65 f32]
#pragma unroll
      for (int nt = 0; nt < 2; ++nt)
#pragma unroll
        for (int r = 0; r < 4; ++r)
          ol[(nt * 16 + c15) * 65 + (wv * 16 + g * 4 + r)] = acc[nt][r];
      __syncthreads();                             // ol visible + W reads done
      unsigned short* dst0 = (type == 0) ? q : k;
      int sl = t >> 3, dch = (t & 7) * 8;          // 32 rows x 8 chunks
      ushort8 p0;
#pragma unroll
      for (int j = 0; j < 8; ++j) p0[j] = f2bf(ol[sl * 65 + dch + j]);
      unsigned short* dst = dst0 + (bh * 4096 + s0 + sl) * 64 + dch;
      *(ushort8*)dst = p0;
    }

    if (yy < 11) {                                 // stage W(yy+1): post-barrier safe
#pragma unroll
      for (int i = 0; i < 8; ++i) {
        int I = wv * 8 + i;
        int u = ((2 * i) & 7) << 4;
        gld16((const char*)wbf + (size_t)(yy + 1) * 32768 + (size_t)I * 1024 + (vb ^ u),
              smem + I * 1024);
      }
      asm volatile("s_waitcnt vmcnt(0)" ::: "memory");
      __syncthreads();                             // W(yy+1) resident; ol reads done
    }
  }
}

// ---------------- kernel 3: flash attention (quad barriers, 8-slot ring) ----
// grid 256 = (xcd-grouped bh, 16 s-tiles of 256); 8 waves x 32 q-rows.
// LDS 128KB = ring 8 x 16K; Q staged via slots 6,7 then released. Quad loop:
// stage quad q+1 (overwrites quad q-1's slots, post-barrier safe); 2x
// pair_body (T15); one vmcnt(0)+s_barrier per 4 tiles (16 barriers).
__global__ __launch_bounds__(512) void k_attn(const unsigned short* __restrict__ qg,
                                              const unsigned short* __restrict__ kg,
                                              const unsigned short* __restrict__ vg,
                                              float* __restrict__ out) {
  __shared__ __align__(16) unsigned char smem[131072];
  const int t = threadIdx.x;
  const int lane = t & 63, wv = t >> 6;
  const int l31 = lane & 31, hi = lane >> 5;

  const int blk = blockIdx.x;
  const int xcd = blk & 7, idx = blk >> 3;
  const int bh = xcd * 2 + (idx & 1);            // same-bh blocks share an XCD L2
  const int s0 = (idx >> 1) * 256;

  const char* qsrc = (const char*)qg + (size_t)bh * 524288 + (size_t)s0 * 128;
  const char* ksrc = (const char*)kg + (size_t)bh * 524288;
  const char* vsrc = (const char*)vg + (size_t)bh * 524288;
  const int vQK = ((lane >> 3) << 7) + (((lane & 7) ^ (lane >> 3)) << 4);
  const int vV  = ((lane >> 3) << 13) + (((lane & 7) ^ (lane >> 3)) << 4);
  // K source offset with row permutation pi (bits[3:2]: 01<->10):
  int kpoff[2];
  {
#pragma unroll
    for (int i = 0; i < 2; ++i) {
      int I = (wv & 3) * 2 + i;
      int srb = I * 8 + (lane >> 3);
      if (((srb >> 2) + 1) & 2) srb ^= 12;         // pi: swap groups 4-7 <-> 8-11
      kpoff[i] = srb * 128 + (((lane & 7) ^ (lane >> 3)) << 4);
    }
  }

  auto stage = [&](int tt, int bufid) {
    unsigned char* tb = smem + bufid * 16384;
    if (wv < 4) {
#pragma unroll
      for (int i = 0; i < 2; ++i) {
        int I = wv * 2 + i;
        gld16(ksrc + (size_t)tt * 8192 + kpoff[i], tb + I * 1024);
      }
    } else {
#pragma unroll
      for (int i = 0; i < 2; ++i) {
        int I = (wv - 4) * 2 + i;
        gld16(vsrc + (size_t)tt * 128 + (size_t)I * 65536 + vV, tb + 8192 + I * 1024);
      }
    }
  };

  // prologue: Q -> slots 6,7 (32KB); tiles 0..3 -> slots 0..3
#pragma unroll
  for (int i = 0; i < 4; ++i) {
    int I = wv * 4 + i;
    gld16(qsrc + (size_t)I * 1024 + vQK, smem + 98304 + I * 1024);
  }
  stage(0, 0);
  stage(1, 1);
  stage(2, 2);
  stage(3, 3);
  asm volatile("s_waitcnt vmcnt(0)" ::: "memory");
  __builtin_amdgcn_s_barrier();
  asm volatile("" ::: "memory");

  // Q fragments from slots 6,7 (lane holds Q[s=wv*32+l31][d=16ks+8hi+j])
  bf16x8 qf[4];
  {
    int row = wv * 32 + l31;
#pragma unroll
    for (int ks = 0; ks < 4; ++ks)
      qf[ks] = *(const bf16x8*)(smem + 98304 + row * 128 + (((ks * 2 + hi) ^ (row & 7)) << 4));
  }
  // qf reads done before quad-1 staging overwrites slots 6,7 (r15 pattern)
  asm volatile("s_waitcnt lgkmcnt(0)" ::: "memory");
  __builtin_amdgcn_s_barrier();
  asm volatile("" ::: "memory");

  f32x16 O0, O1, lacc;
#pragma unroll
  for (int r = 0; r < 16; ++r) { O0[r] = 0.f; O1[r] = 0.f; lacc[r] = 0.f; }

  uint4v onesu;
  onesu[0] = onesu[1] = onesu[2] = onesu[3] = 0x3F803F80u;  // bf16 1.0 x8
  const bf16x8 onesb = __builtin_bit_cast(bf16x8, onesu);

  // softmax-finish + PV for one tile, given its QK scores (sc0,sc1)
  auto finish_tile = [&](f32x16& sc0, f32x16& sc1, const unsigned char* vbuf) {
#pragma unroll
    for (int r = 0; r < 16; ++r) {
      sc0[r] = __builtin_amdgcn_exp2f(sc0[r]);
      sc1[r] = __builtin_amdgcn_exp2f(sc1[r]);
    }
    uint4v paw[4];
#pragma unroll
    for (int j = 0; j < 4; ++j) {
      paw[0][j] = cvtpk(sc0[2 * j],     sc0[2 * j + 1]);
      paw[1][j] = cvtpk(sc0[8 + 2 * j], sc0[8 + 2 * j + 1]);
      paw[2][j] = cvtpk(sc1[2 * j],     sc1[2 * j + 1]);
      paw[3][j] = cvtpk(sc1[8 + 2 * j], sc1[8 + 2 * j + 1]);
    }
    __builtin_amdgcn_s_setprio(1);
#pragma unroll
    for (int ks = 0; ks < 4; ++ks) {
      bf16x8 pa = __builtin_bit_cast(bf16x8, paw[ks]);
      lacc = __builtin_amdgcn_mfma_f32_32x32x16_bf16(pa, onesb, lacc, 0, 0, 0);
      int sw = ((ks * 2 + hi) ^ (l31 & 7)) << 4;
      bf16x8 v0 = *(const bf16x8*)(vbuf + l31 * 128 + sw);
      O0 = __builtin_amdgcn_mfma_f32_32x32x16_bf16(pa, v0, O0, 0, 0, 0);
      bf16x8 v1 = *(const bf16x8*)(vbuf + (32 + l31) * 128 + sw);
      O1 = __builtin_amdgcn_mfma_f32_32x32x16_bf16(pa, v1, O1, 0, 0, 0);
    }
    __builtin_amdgcn_s_setprio(0);
  };

  // 2-tile pipelined pair (T15)
  auto pair_body = [&](const unsigned char* ka, const unsigned char* kb) {
    f32x16 sa0, sa1, sb0, sb1;
#pragma unroll
    for (int r = 0; r < 16; ++r) { sa0[r] = 0.f; sa1[r] = 0.f; sb0[r] = 0.f; sb1[r] = 0.f; }
    __builtin_amdgcn_s_setprio(1);
#pragma unroll
    for (int ks = 0; ks < 4; ++ks) {
      int sw = ((ks * 2 + hi) ^ (l31 & 7)) << 4;
      bf16x8 a0 = *(const bf16x8*)(ka + l31 * 128 + sw);
      sa0 = __builtin_amdgcn_mfma_f32_32x32x16_bf16(a0, qf[ks], sa0, 0, 0, 0);
      bf16x8 a1 = *(const bf16x8*)(ka + (32 + l31) * 128 + sw);
      sa1 = __builtin_amdgcn_mfma_f32_32x32x16_bf16(a1, qf[ks], sa1, 0, 0, 0);
    }
#pragma unroll
    for (int ks = 0; ks < 4; ++ks) {
      int sw = ((ks * 2 + hi) ^ (l31 & 7)) << 4;
      bf16x8 b0 = *(const bf16x8*)(kb + l31 * 128 + sw);
      sb0 = __builtin_amdgcn_mfma_f32_32x32x16_bf16(b0, qf[ks], sb0, 0, 0, 0);
      bf16x8 b1 = *(const bf16x8*)(kb + (32 + l31) * 128 + sw);
      sb1 = __builtin_amdgcn_mfma_f32_32x32x16_bf16(b1, qf[ks], sb1, 0, 0, 0);
    }
    __builtin_amdgcn_s_setprio(0);
    finish_tile(sa0, sa1, ka + 8192);
    finish_tile(sb0, sb1, kb + 8192);
  };

  // quad loop: 16 quads of 4 tiles; one vmcnt(0)+barrier per quad.
  // Quad q reads slots (4q)&7..(4q+3)&7; stages quad q+1 into the other 4
  // (quad q-1's slots, all reads certified by the previous barrier).
#pragma unroll 2
  for (int qd = 0; qd < 16; ++qd) {
    if (qd < 15) {
      stage(4 * qd + 4, (4 * qd + 4) & 7);
      stage(4 * qd + 5, (4 * qd + 5) & 7);
      stage(4 * qd + 6, (4 * qd + 6) & 7);
      stage(4 * qd + 7, (4 * qd + 7) & 7);
    }
    pair_body(smem + ((4 * qd) & 7) * 16384,
              smem + ((4 * qd + 1) & 7) * 16384);
    pair_body(smem + ((4 * qd + 2) & 7) * 16384,
              smem + ((4 * qd + 3) & 7) * 16384);
    asm volatile("s_waitcnt vmcnt(0)" ::: "memory");  // quad q+1 resident
    __builtin_amdgcn_s_barrier();
    asm volatile("" ::: "memory");
  }

  // epilogue: normalize (lacc already per-O-row), transpose via per-wave LDS
  float rn[16];
#pragma unroll
  for (int r = 0; r < 16; ++r) rn[r] = 1.0f / lacc[r];
  float* ep = (float*)(smem + wv * 4608);          // [32 d][36 f32] per wave
  const size_t outbase = (size_t)bh * 262144 + (size_t)(s0 + wv * 32);
#pragma unroll
  for (int dt = 0; dt < 2; ++dt) {
    const f32x16& O = dt ? O1 : O0;
#pragma unroll
    for (int g4 = 0; g4 < 4; ++g4) {
      f32x4 w;
      w[0] = O[4 * g4 + 0] * rn[4 * g4 + 0];
      w[1] = O[4 * g4 + 1] * rn[4 * g4 + 1];
      w[2] = O[4 * g4 + 2] * rn[4 * g4 + 2];
      w[3] = O[4 * g4 + 3] * rn[4 * g4 + 3];
      *(f32x4*)(ep + l31 * 36 + g4 * 8 + hi * 4) = w;   // [d=l31][s_local]
    }
#pragma unroll
    for (int j = 0; j < 4; ++j) {
      int idx2 = j * 64 + lane;
      int d = idx2 >> 3, s4c = idx2 & 7;
      f32x4 vv = *(const f32x4*)(ep + d * 36 + s4c * 4);
      *(f32x4*)(out + outbase + (size_t)(dt * 32 + d) * 4096 + s4c * 4) = vv;
    }
  }
}

// ---------------------------------------------------------------------------
extern "C" void kernel_launch(void* const* d_in, const int* in_sizes, int n_in,
                              void* d_out, int out_size, void* d_ws, size_t ws_size,
                              hipStream_t stream) {
  const float* x = (const float*)d_in[0];
  const float* wdw = (const float*)d_in[1];
  const float* wpw = (const float*)d_in[2];
  float* out = (float*)d_out;
  char* ws = (char*)d_ws;
  unsigned short* dwt = (unsigned short*)(ws + OFF_DW);
  unsigned short* wbf = (unsigned short*)(ws + OFF_WB);
  unsigned short* q = (unsigned short*)(ws + OFF_Q);
  unsigned short* k = (unsigned short*)(ws + OFF_K);
  unsigned short* v = (unsigned short*)(ws + OFF_V);

  k_dw<<<dim3(64, 4, 4), dim3(512), 0, stream>>>(x, wdw, wpw, dwt, wbf);
  k_pw<<<dim3(128, 4), dim3(256), 0, stream>>>(dwt, wbf, q, k, v);
  k_attn<<<dim3(256), dim3(512), 0, stream>>>(q, k, v, out);
}

// Round 22
// 117.414 us; speedup vs baseline: 1.0258x; 1.0258x over previous
//
#include <hip/hip_runtime.h>

// ---------------------------------------------------------------------------
// BasicAttention: dwconv3x3 -> pointwise 1x1 (C->3C) -> 4-head attention S=4096
// B=4, C=256, H=W=64, heads=4, d=64. Output f32 [B,C,H,W].
//
//  k_dw   : depthwise conv -> DWt bf16 (coalesced lane=w) + folded w_pw cvt
//  k_pw   : 256 thr / 4 waves, 32-s tiles, 2 blocks/CU (r20)
//  k_attn : flash attention, swapped QK^T, no-max softmax (r10), permuted-K
//           (r11), l via ones-MFMA, 4-slot KV ring + pair barriers (r12/13),
//           2-tile pipelined pair body (r17). FINAL (r22 = r20, best 117.6us).
//  Plateau map: barriers 64->32 -4us (r12), 32->16 +3-6us (r21); occupancy
//  x2 null (r15); ring depth null (r8,r14); split-K negative (r15); LDS-
//  volume halving failed twice (r9 spill, r18 numeric). k_attn 80.8us =
//  dep-chain floor for this structure (MFMA 46% / VALU 34% / LDS ~55%).
// ---------------------------------------------------------------------------

typedef __attribute__((ext_vector_type(8))) __bf16 bf16x8;
typedef __attribute__((ext_vector_type(4))) float f32x4;
typedef __attribute__((ext_vector_type(16))) float f32x16;
typedef __attribute__((ext_vector_type(8))) unsigned short ushort8;
typedef __attribute__((ext_vector_type(4))) unsigned int uint4v;

#define OFF_DW 0ull
#define OFF_WB 8388608ull
#define OFF_Q  8781824ull
#define OFF_K  17170432ull
#define OFF_V  25559040ull

__device__ __forceinline__ unsigned short f2bf(float x) {
  unsigned u = __builtin_bit_cast(unsigned, x);
  u += 0x7fffu + ((u >> 16) & 1u);           // RNE
  return (unsigned short)(u >> 16);
}

__device__ __forceinline__ void gld16(const void* g, void* l) {
  __builtin_amdgcn_global_load_lds((const __attribute__((address_space(1))) void*)g,
                                   (__attribute__((address_space(3))) void*)l, 16, 0, 0);
}

__device__ __forceinline__ unsigned cvtpk(float lo, float hi) {
  unsigned r;
  asm("v_cvt_pk_bf16_f32 %0, %1, %2" : "=v"(r) : "v"(lo), "v"(hi));
  return r;
}

// ---------------- kernel 1: depthwise conv + w_pw conversion ----------------
__global__ __launch_bounds__(512) void k_dw(const float* __restrict__ x,
                                            const float* __restrict__ wdw,
                                            const float* __restrict__ wpw,
                                            unsigned short* __restrict__ dwt,
                                            unsigned short* __restrict__ wbf) {
  __shared__ float tile[64 * 65];
  const int t = threadIdx.x;
  const int h = blockIdx.x;
  const int c0 = blockIdx.y * 64;
  const int b = blockIdx.z;

  {
    int bid = blockIdx.x + 64 * blockIdx.y + 256 * blockIdx.z;   // 0..1023
    if (t < 192) {
      int idx = bid * 192 + t;
      int o = idx >> 8;
      float v = wpw[idx];
      if (o < 256) v *= 0.18033688011112042f;     // 0.125 * log2(e)
      wbf[idx] = f2bf(v);
    }
  }

  const int w = t & 63;
  const int wq = t >> 6;                          // 0..7
#pragma unroll
  for (int i = 0; i < 8; ++i) {
    int cl = wq * 8 + i;
    int c = c0 + cl;
    const float* wd = wdw + c * 9;
    const float* xb = x + ((size_t)(b * 256 + c) << 12);
    float acc = 0.f;
#pragma unroll
    for (int ky = 0; ky < 3; ++ky) {
      int hh = h + ky - 1;
      if ((unsigned)hh < 64u) {
        const float* row = xb + hh * 64;
#pragma unroll
        for (int kx = 0; kx < 3; ++kx) {
          int ww = w + kx - 1;
          if ((unsigned)ww < 64u) acc += row[ww] * wd[ky * 3 + kx];
        }
      }
    }
    tile[w * 65 + cl] = acc;
  }
  __syncthreads();
  int sl = t >> 3, cch = (t & 7) * 8;             // 64 rows x 8 chunks
  ushort8 p0;
#pragma unroll
  for (int j = 0; j < 8; ++j) p0[j] = f2bf(tile[sl * 65 + cch + j]);
  unsigned short* dst = dwt + ((size_t)(b * 4096 + h * 64 + sl)) * 256 + c0 + cch;
  *(ushort8*)dst = p0;
}

// ---------------- kernel 2: pointwise GEMM -> Q,K,Vt (2 blocks/CU) ----------
// grid (128 s-tiles of 32, 4 b), 256 thr / 4 waves. Wave = 16o x 32s.
// LDS: W [0,32K) single-buffer | DWt [32K,48K) | ol [48K,+8.3K) = 57.5KB.
__global__ __launch_bounds__(256) void k_pw(const unsigned short* __restrict__ dwt,
                                            const unsigned short* __restrict__ wbf,
                                            unsigned short* __restrict__ q,
                                            unsigned short* __restrict__ k,
                                            unsigned short* __restrict__ v) {
  __shared__ __align__(16) unsigned char smem[57472];
  const int t = threadIdx.x;
  const int lane = t & 63, wv = t >> 6;            // wv 0..3
  const int s0 = blockIdx.x * 32;
  const int b = blockIdx.y;
  const int vb = ((lane >> 5) << 9) + (((lane & 31) ^ (lane >> 5)) << 4);
  const char* dsrc = (const char*)dwt + ((size_t)(b * 4096 + s0)) * 512;

  // prologue: stage DWt (16KB, 4 gld16/wave) + W(0) (32KB, 8 gld16/wave)
#pragma unroll
  for (int i = 0; i < 4; ++i) {
    int I = wv * 4 + i;
    int u = ((2 * i) & 7) << 4;                    // (2I)&7 == (2i)&7
    gld16(dsrc + (size_t)I * 1024 + (vb ^ u), smem + 32768 + I * 1024);
  }
#pragma unroll
  for (int i = 0; i < 8; ++i) {
    int I = wv * 8 + i;
    int u = ((2 * i) & 7) << 4;
    gld16((const char*)wbf + (size_t)I * 1024 + (vb ^ u), smem + I * 1024);
  }
  asm volatile("s_waitcnt vmcnt(0)" ::: "memory");
  __syncthreads();

  const int c15 = lane & 15, g = lane >> 4;
  const int orow = wv * 16 + c15;                  // wave owns 16 o-rows

#pragma unroll 1
  for (int yy = 0; yy < 12; ++yy) {
    f32x4 acc[2] = {{0,0,0,0},{0,0,0,0}};
#pragma unroll
    for (int kc = 0; kc < 8; ++kc) {
      bf16x8 a = *(const bf16x8*)(smem + orow * 512 + (((kc * 4 + g) ^ (orow & 7)) << 4));
#pragma unroll
      for (int nt = 0; nt < 2; ++nt) {
        int srow = nt * 16 + c15;
        bf16x8 bb = *(const bf16x8*)(smem + 32768 + srow * 512 + (((kc * 4 + g) ^ (srow & 7)) << 4));
        acc[nt] = __builtin_amdgcn_mfma_f32_16x16x32_bf16(a, bb, acc[nt], 0, 0, 0);
      }
    }

    const int type = yy >> 2, head = yy & 3;
    const size_t bh = (size_t)(b * 4 + head);
    if (type == 2) {
#pragma unroll
      for (int nt = 0; nt < 2; ++nt)
#pragma unroll
        for (int r = 0; r < 4; ++r) {
          int d = wv * 16 + g * 4 + r;
          int sg = s0 + nt * 16 + c15;
          v[(bh * 64 + d) * 4096 + sg] = f2bf(acc[nt][r]);
        }
      __syncthreads();                             // all W(yy) reads done
    } else {
      float* ol = (float*)(smem + 49152);          // [32 s][65 f32]
#pragma unroll
      for (int nt = 0; nt < 2; ++nt)
#pragma unroll
        for (int r = 0; r < 4; ++r)
          ol[(nt * 16 + c15) * 65 + (wv * 16 + g * 4 + r)] = acc[nt][r];
      __syncthreads();                             // ol visible + W reads done
      unsigned short* dst0 = (type == 0) ? q : k;
      int sl = t >> 3, dch = (t & 7) * 8;          // 32 rows x 8 chunks
      ushort8 p0;
#pragma unroll
      for (int j = 0; j < 8; ++j) p0[j] = f2bf(ol[sl * 65 + dch + j]);
      unsigned short* dst = dst0 + (bh * 4096 + s0 + sl) * 64 + dch;
      *(ushort8*)dst = p0;
    }

    if (yy < 11) {                                 // stage W(yy+1): post-barrier safe
#pragma unroll
      for (int i = 0; i < 8; ++i) {
        int I = wv * 8 + i;
        int u = ((2 * i) & 7) << 4;
        gld16((const char*)wbf + (size_t)(yy + 1) * 32768 + (size_t)I * 1024 + (vb ^ u),
              smem + I * 1024);
      }
      asm volatile("s_waitcnt vmcnt(0)" ::: "memory");
      __syncthreads();                             // W(yy+1) resident; ol reads done
    }
  }
}

// ---------------- kernel 3: flash attention (2-tile pipelined pairs) --------
// grid 256 = (xcd-grouped bh, 16 s-tiles of 256); 8 waves x 32 q-rows.
// LDS 96KB: Q 32K | KV ring 4 x 16K. Pair loop: stage pair p+1 early;
// pair body interleaved QK_a,QK_b,SM_a,PV_a,SM_b,PV_b (T15 pipeline);
// vmcnt(0)+s_barrier once per pair.
__global__ __launch_bounds__(512) void k_attn(const unsigned short* __restrict__ qg,
                                              const unsigned short* __restrict__ kg,
                                              const unsigned short* __restrict__ vg,
                                              float* __restrict__ out) {
  __shared__ __align__(16) unsigned char smem[98304];
  const int t = threadIdx.x;
  const int lane = t & 63, wv = t >> 6;
  const int l31 = lane & 31, hi = lane >> 5;

  const int blk = blockIdx.x;
  const int xcd = blk & 7, idx = blk >> 3;
  const int bh = xcd * 2 + (idx & 1);            // same-bh blocks share an XCD L2
  const int s0 = (idx >> 1) * 256;

  const char* qsrc = (const char*)qg + (size_t)bh * 524288 + (size_t)s0 * 128;
  const char* ksrc = (const char*)kg + (size_t)bh * 524288;
  const char* vsrc = (const char*)vg + (size_t)bh * 524288;
  const int vQK = ((lane >> 3) << 7) + (((lane & 7) ^ (lane >> 3)) << 4);
  const int vV  = ((lane >> 3) << 13) + (((lane & 7) ^ (lane >> 3)) << 4);
  // K source offset with row permutation pi (bits[3:2]: 01<->10):
  int kpoff[2];
  {
#pragma unroll
    for (int i = 0; i < 2; ++i) {
      int I = (wv & 3) * 2 + i;
      int srb = I * 8 + (lane >> 3);
      if (((srb >> 2) + 1) & 2) srb ^= 12;         // pi: swap groups 4-7 <-> 8-11
      kpoff[i] = srb * 128 + (((lane & 7) ^ (lane >> 3)) << 4);
    }
  }

  auto stage = [&](int tt, int bufid) {
    unsigned char* tb = smem + 32768 + bufid * 16384;
    if (wv < 4) {
#pragma unroll
      for (int i = 0; i < 2; ++i) {
        int I = wv * 2 + i;
        gld16(ksrc + (size_t)tt * 8192 + kpoff[i], tb + I * 1024);
      }
    } else {
#pragma unroll
      for (int i = 0; i < 2; ++i) {
        int I = (wv - 4) * 2 + i;
        gld16(vsrc + (size_t)tt * 128 + (size_t)I * 65536 + vV, tb + 8192 + I * 1024);
      }
    }
  };

  // prologue: stage Q + pair 0 (tiles 0,1)
#pragma unroll
  for (int i = 0; i < 4; ++i) {
    int I = wv * 4 + i;
    gld16(qsrc + (size_t)I * 1024 + vQK, smem + I * 1024);
  }
  stage(0, 0);
  stage(1, 1);
  asm volatile("s_waitcnt vmcnt(0)" ::: "memory");
  __builtin_amdgcn_s_barrier();
  asm volatile("" ::: "memory");

  // Q fragments (B-operand: lane holds Q[s=wv*32+l31][d = 16*ks + 8*hi + j])
  bf16x8 qf[4];
  {
    int row = wv * 32 + l31;
#pragma unroll
    for (int ks = 0; ks < 4; ++ks)
      qf[ks] = *(const bf16x8*)(smem + row * 128 + (((ks * 2 + hi) ^ (row & 7)) << 4));
  }

  f32x16 O0, O1, lacc;
#pragma unroll
  for (int r = 0; r < 16; ++r) { O0[r] = 0.f; O1[r] = 0.f; lacc[r] = 0.f; }

  uint4v onesu;
  onesu[0] = onesu[1] = onesu[2] = onesu[3] = 0x3F803F80u;  // bf16 1.0 x8
  const bf16x8 onesb = __builtin_bit_cast(bf16x8, onesu);

  // softmax-finish + PV for one tile, given its QK scores (sc0,sc1)
  auto finish_tile = [&](f32x16& sc0, f32x16& sc1, const unsigned char* vbuf) {
#pragma unroll
    for (int r = 0; r < 16; ++r) {
      sc0[r] = __builtin_amdgcn_exp2f(sc0[r]);
      sc1[r] = __builtin_amdgcn_exp2f(sc1[r]);
    }
    uint4v paw[4];
#pragma unroll
    for (int j = 0; j < 4; ++j) {
      paw[0][j] = cvtpk(sc0[2 * j],     sc0[2 * j + 1]);
      paw[1][j] = cvtpk(sc0[8 + 2 * j], sc0[8 + 2 * j + 1]);
      paw[2][j] = cvtpk(sc1[2 * j],     sc1[2 * j + 1]);
      paw[3][j] = cvtpk(sc1[8 + 2 * j], sc1[8 + 2 * j + 1]);
    }
    __builtin_amdgcn_s_setprio(1);
#pragma unroll
    for (int ks = 0; ks < 4; ++ks) {
      bf16x8 pa = __builtin_bit_cast(bf16x8, paw[ks]);
      lacc = __builtin_amdgcn_mfma_f32_32x32x16_bf16(pa, onesb, lacc, 0, 0, 0);
      int sw = ((ks * 2 + hi) ^ (l31 & 7)) << 4;
      bf16x8 v0 = *(const bf16x8*)(vbuf + l31 * 128 + sw);
      O0 = __builtin_amdgcn_mfma_f32_32x32x16_bf16(pa, v0, O0, 0, 0, 0);
      bf16x8 v1 = *(const bf16x8*)(vbuf + (32 + l31) * 128 + sw);
      O1 = __builtin_amdgcn_mfma_f32_32x32x16_bf16(pa, v1, O1, 0, 0, 0);
    }
    __builtin_amdgcn_s_setprio(0);
  };

  // 2-tile pipelined pair (T15)
  auto pair_body = [&](const unsigned char* ka, const unsigned char* kb) {
    f32x16 sa0, sa1, sb0, sb1;
#pragma unroll
    for (int r = 0; r < 16; ++r) { sa0[r] = 0.f; sa1[r] = 0.f; sb0[r] = 0.f; sb1[r] = 0.f; }
    __builtin_amdgcn_s_setprio(1);
#pragma unroll
    for (int ks = 0; ks < 4; ++ks) {
      int sw = ((ks * 2 + hi) ^ (l31 & 7)) << 4;
      bf16x8 a0 = *(const bf16x8*)(ka + l31 * 128 + sw);
      sa0 = __builtin_amdgcn_mfma_f32_32x32x16_bf16(a0, qf[ks], sa0, 0, 0, 0);
      bf16x8 a1 = *(const bf16x8*)(ka + (32 + l31) * 128 + sw);
      sa1 = __builtin_amdgcn_mfma_f32_32x32x16_bf16(a1, qf[ks], sa1, 0, 0, 0);
    }
#pragma unroll
    for (int ks = 0; ks < 4; ++ks) {
      int sw = ((ks * 2 + hi) ^ (l31 & 7)) << 4;
      bf16x8 b0 = *(const bf16x8*)(kb + l31 * 128 + sw);
      sb0 = __builtin_amdgcn_mfma_f32_32x32x16_bf16(b0, qf[ks], sb0, 0, 0, 0);
      bf16x8 b1 = *(const bf16x8*)(kb + (32 + l31) * 128 + sw);
      sb1 = __builtin_amdgcn_mfma_f32_32x32x16_bf16(b1, qf[ks], sb1, 0, 0, 0);
    }
    __builtin_amdgcn_s_setprio(0);
    finish_tile(sa0, sa1, ka + 8192);
    finish_tile(sb0, sb1, kb + 8192);
  };

  // pair loop: 32 pairs; unroll 2 -> all ring indices compile-time
#pragma unroll 2
  for (int p = 0; p < 32; ++p) {
    if (p < 31) {                                 // stage pair p+1 early (T14)
      stage(2 * p + 2, (2 * p + 2) & 3);
      stage(2 * p + 3, (2 * p + 3) & 3);
    }
    pair_body(smem + 32768 + ((2 * p) & 3) * 16384,
              smem + 32768 + ((2 * p + 1) & 3) * 16384);
    asm volatile("s_waitcnt vmcnt(0)" ::: "memory");  // pair p+1 resident
    __builtin_amdgcn_s_barrier();
    asm volatile("" ::: "memory");
  }

  // epilogue: normalize (lacc already per-O-row), transpose via per-wave LDS
  float rn[16];
#pragma unroll
  for (int r = 0; r < 16; ++r) rn[r] = 1.0f / lacc[r];
  float* ep = (float*)(smem + wv * 4608);          // [32 d][36 f32] per wave
  const size_t outbase = (size_t)bh * 262144 + (size_t)(s0 + wv * 32);
#pragma unroll
  for (int dt = 0; dt < 2; ++dt) {
    const f32x16& O = dt ? O1 : O0;
#pragma unroll
    for (int g4 = 0; g4 < 4; ++g4) {
      f32x4 w;
      w[0] = O[4 * g4 + 0] * rn[4 * g4 + 0];
      w[1] = O[4 * g4 + 1] * rn[4 * g4 + 1];
      w[2] = O[4 * g4 + 2] * rn[4 * g4 + 2];
      w[3] = O[4 * g4 + 3] * rn[4 * g4 + 3];
      *(f32x4*)(ep + l31 * 36 + g4 * 8 + hi * 4) = w;   // [d=l31][s_local]
    }
#pragma unroll
    for (int j = 0; j < 4; ++j) {
      int idx2 = j * 64 + lane;
      int d = idx2 >> 3, s4c = idx2 & 7;
      f32x4 vv = *(const f32x4*)(ep + d * 36 + s4c * 4);
      *(f32x4*)(out + outbase + (size_t)(dt * 32 + d) * 4096 + s4c * 4) = vv;
    }
  }
}

// ---------------------------------------------------------------------------
extern "C" void kernel_launch(void* const* d_in, const int* in_sizes, int n_in,
                              void* d_out, int out_size, void* d_ws, size_t ws_size,
                              hipStream_t stream) {
  const float* x = (const float*)d_in[0];
  const float* wdw = (const float*)d_in[1];
  const float* wpw = (const float*)d_in[2];
  float* out = (float*)d_out;
  char* ws = (char*)d_ws;
  unsigned short* dwt = (unsigned short*)(ws + OFF_DW);
  unsigned short* wbf = (unsigned short*)(ws + OFF_WB);
  unsigned short* q = (unsigned short*)(ws + OFF_Q);
  unsigned short* k = (unsigned short*)(ws + OFF_K);
  unsigned short* v = (unsigned short*)(ws + OFF_V);

  k_dw<<<dim3(64, 4, 4), dim3(512), 0, stream>>>(x, wdw, wpw, dwt, wbf);
  k_pw<<<dim3(128, 4), dim3(256), 0, stream>>>(dwt, wbf, q, k, v);
  k_attn<<<dim3(256), dim3(512), 0, stream>>>(q, k, v, out);
}